// Round 1
// baseline (387.555 us; speedup 1.0000x reference)
//
#include <hip/hip_runtime.h>

#define N_PP 100000
#define N_A  50000
#define N_AP 150000
#define BSZ  8192
#define NEDGE 500000
#define EPSF 1e-12f

// ---------------- block reduction (256 threads = 4 waves) ----------------
__device__ __forceinline__ float block_reduce_sum_256(float v) {
#pragma unroll
    for (int o = 32; o > 0; o >>= 1) v += __shfl_down(v, o, 64);
    __shared__ float red[4];
    int lane = threadIdx.x & 63;
    int wid  = threadIdx.x >> 6;
    if (lane == 0) red[wid] = v;
    __syncthreads();
    float r = 0.f;
    if (threadIdx.x == 0) r = red[0] + red[1] + red[2] + red[3];
    return r;
}

// ---------------- edge (link) term ----------------
// term_i = w[e0] + w[e1 + w1_off] - sqrt(||xvec[e0] - yvec[e1 + y_off]||^2 + eps)
__global__ __launch_bounds__(256) void edge_kernel(
        const float* __restrict__ xvec, const float* __restrict__ yvec,
        const float* __restrict__ w, const int* __restrict__ e,
        int w1_off, int y_off, double* __restrict__ acc)
{
    int i = blockIdx.x * blockDim.x + threadIdx.x;
    float term = 0.f;
    if (i < NEDGE) {
        int i0 = e[i];
        int i1 = e[NEDGE + i];
        const float* xv = xvec + (size_t)i0 * 16;
        const float* yv = yvec + (size_t)(i1 + y_off) * 16;
        float d2 = 0.f;
#pragma unroll
        for (int c = 0; c < 16; c += 4) {
            float4 xq = *(const float4*)(xv + c);
            float4 yq = *(const float4*)(yv + c);
            float dx = xq.x - yq.x; d2 = fmaf(dx, dx, d2);
            float dy = xq.y - yq.y; d2 = fmaf(dy, dy, d2);
            float dz = xq.z - yq.z; d2 = fmaf(dz, dz, d2);
            float dw = xq.w - yq.w; d2 = fmaf(dw, dw, d2);
        }
        term = w[i0] + w[i1 + w1_off] - sqrtf(d2 + EPSF);
    }
    float bs = block_reduce_sum_256(term);
    if (threadIdx.x == 0) atomicAdd(acc, (double)bs);
}

// ---------------- pairwise (non-link) term ----------------
// rows i = xn (p_star_nodes) indexed by blockIdx.y; cols j = yn indexed by blockIdx.x
// val = exp(wX[xn[i]+wx_off] + wY[yn[j]+wy_off] - sqrt(max(xx+yy-2*dot, eps)))
// TRIU: only count pairs with global j > i.
template <bool TRIU>
__global__ __launch_bounds__(256) void pair_kernel(
        const float* __restrict__ X, const float* __restrict__ Y,
        const float* __restrict__ wX, const float* __restrict__ wY,
        const int* __restrict__ xn, const int* __restrict__ yn,
        int y_voff, int wx_off, int wy_off, double* __restrict__ acc)
{
    const int bx = blockIdx.x, by = blockIdx.y;
    if (TRIU && by > bx) return;   // whole block strictly below diagonal

    __shared__ float xs[64 * 17];
    __shared__ float ys[64 * 17];
    __shared__ float xx[64], yy[64], gx[64], gy[64];

    const int t = threadIdx.x;
    {
        int r  = t >> 2;            // 0..63
        int c4 = (t & 3) << 2;      // 0,4,8,12
        int xnode = xn[by * 64 + r];
        int ynode = yn[bx * 64 + r];
        float4 xv = *(const float4*)(X + (size_t)xnode * 16 + c4);
        float4 yv = *(const float4*)(Y + (size_t)(ynode + y_voff) * 16 + c4);
        xs[r * 17 + c4 + 0] = xv.x;
        xs[r * 17 + c4 + 1] = xv.y;
        xs[r * 17 + c4 + 2] = xv.z;
        xs[r * 17 + c4 + 3] = xv.w;
        ys[r * 17 + c4 + 0] = yv.x;
        ys[r * 17 + c4 + 1] = yv.y;
        ys[r * 17 + c4 + 2] = yv.z;
        ys[r * 17 + c4 + 3] = yv.w;
        if (c4 == 0) {
            gx[r] = wX[xnode + wx_off];
            gy[r] = wY[ynode + wy_off];
        }
    }
    __syncthreads();
    if (t < 64) {
        float s = 0.f;
#pragma unroll
        for (int c = 0; c < 16; ++c) { float v = xs[t * 17 + c]; s = fmaf(v, v, s); }
        xx[t] = s;
    } else if (t < 128) {
        int r = t - 64;
        float s = 0.f;
#pragma unroll
        for (int c = 0; c < 16; ++c) { float v = ys[r * 17 + c]; s = fmaf(v, v, s); }
        yy[r] = s;
    }
    __syncthreads();

    const int tx = t & 15;   // column group
    const int ty = t >> 4;   // row group
    float dot[4][4];
#pragma unroll
    for (int di = 0; di < 4; ++di)
#pragma unroll
        for (int dj = 0; dj < 4; ++dj) dot[di][dj] = 0.f;

#pragma unroll
    for (int k = 0; k < 16; ++k) {
        float xr[4], yr[4];
#pragma unroll
        for (int d = 0; d < 4; ++d) {
            xr[d] = xs[(ty * 4 + d) * 17 + k];
            yr[d] = ys[(tx * 4 + d) * 17 + k];
        }
#pragma unroll
        for (int di = 0; di < 4; ++di)
#pragma unroll
            for (int dj = 0; dj < 4; ++dj)
                dot[di][dj] = fmaf(xr[di], yr[dj], dot[di][dj]);
    }

    float s = 0.f;
#pragma unroll
    for (int di = 0; di < 4; ++di) {
#pragma unroll
        for (int dj = 0; dj < 4; ++dj) {
            int il = ty * 4 + di;
            int jl = tx * 4 + dj;
            float sq = xx[il] + yy[jl] - 2.0f * dot[di][dj];
            float dist = sqrtf(fmaxf(sq, EPSF));
            float v = expf(gx[il] + gy[jl] - dist);
            bool keep = !TRIU || ((bx * 64 + jl) > (by * 64 + il));
            s += keep ? v : 0.f;
        }
    }

    float bs = block_reduce_sum_256(s);
    if (t == 0) atomicAdd(acc, (double)bs);
}

// ---------------- finalize ----------------
__global__ void finalize_kernel(const double* __restrict__ acc, float* __restrict__ out)
{
    // acc[0]=link_pp acc[1]=nonlink_pp acc[2]=link_ap acc[3]=nonlink_ap
    double nll_pp = -(acc[0] - acc[1]);
    double nll_ap = -(acc[2] - acc[3]);
    out[0] = (float)(0.5 * nll_pp / (double)BSZ + 0.5 * nll_ap / (double)BSZ);
}

extern "C" void kernel_launch(void* const* d_in, const int* in_sizes, int n_in,
                              void* d_out, int out_size, void* d_ws, size_t ws_size,
                              hipStream_t stream)
{
    const float* p       = (const float*)d_in[0];
    const float* p_star  = (const float*)d_in[1];
    const float* a       = (const float*)d_in[2];
    const float* beta    = (const float*)d_in[3];
    const float* gamma   = (const float*)d_in[4];
    const int* edges_pp  = (const int*)d_in[5];
    const int* edges_ap  = (const int*)d_in[6];
    const int* psn       = (const int*)d_in[7];
    const int* pn        = (const int*)d_in[8];
    const int* an        = (const int*)d_in[9];

    double* acc = (double*)d_ws;
    hipMemsetAsync(d_ws, 0, 4 * sizeof(double), stream);

    int eb = (NEDGE + 255) / 256;
    // pp link: w idx e0 and e1+N_PP ; vectors p_star[e0], p[e1]
    edge_kernel<<<eb, 256, 0, stream>>>(p_star, p, gamma, edges_pp, N_PP, 0, acc + 0);
    // ap link: w idx e0 and e1 ; vectors p_star[e0], a[e1 - N_PP]
    edge_kernel<<<eb, 256, 0, stream>>>(p_star, a, beta, edges_ap, 0, -N_PP, acc + 2);

    dim3 grid(BSZ / 64, BSZ / 64);
    // pp nonlink: rows p_star_nodes (gamma[.]), cols p_nodes (gamma[.+N_PP]), triu k=1
    pair_kernel<true><<<grid, 256, 0, stream>>>(p_star, p, gamma, gamma, psn, pn,
                                                0, 0, N_PP, acc + 1);
    // ap nonlink: rows p_star_nodes (beta[.]), cols a_nodes (beta[.], vec a[.-N_PP]), full
    pair_kernel<false><<<grid, 256, 0, stream>>>(p_star, a, beta, beta, psn, an,
                                                 -N_PP, 0, 0, acc + 3);

    finalize_kernel<<<1, 1, 0, stream>>>(acc, (float*)d_out);
}

// Round 2
// 164.056 us; speedup vs baseline: 2.3623x; 2.3623x over previous
//
#include <hip/hip_runtime.h>

#define N_PP 100000
#define N_A  50000
#define N_AP 150000
#define BSZ  8192
#define NEDGE 500000
#define TILE 128
#define KD 16
#define SCALE 1.44269504088896f          // log2(e)
#define EPS2  (1e-12f * SCALE * SCALE)   // eps scaled into the squared domain

#if __has_builtin(__builtin_amdgcn_sqrtf)
#define FAST_SQRT(x) __builtin_amdgcn_sqrtf(x)
#else
#define FAST_SQRT(x) sqrtf(x)
#endif
#if __has_builtin(__builtin_amdgcn_exp2f)
#define FAST_EXP2(x) __builtin_amdgcn_exp2f(x)
#else
#define FAST_EXP2(x) exp2f(x)
#endif

// ---------------- block reduction (256 threads = 4 waves) ----------------
__device__ __forceinline__ float block_reduce_sum_256(float v, float* red) {
#pragma unroll
    for (int o = 32; o > 0; o >>= 1) v += __shfl_down(v, o, 64);
    int lane = threadIdx.x & 63;
    int wid  = threadIdx.x >> 6;
    if (lane == 0) red[wid] = v;
    __syncthreads();
    float r = 0.f;
    if (threadIdx.x == 0) r = red[0] + red[1] + red[2] + red[3];
    return r;
}

// ---------------- edge (link) term ----------------
__global__ __launch_bounds__(256) void edge_kernel(
        const float* __restrict__ xvec, const float* __restrict__ yvec,
        const float* __restrict__ w, const int* __restrict__ e,
        int w1_off, int y_off, double* __restrict__ acc)
{
    __shared__ float red[4];
    int i = blockIdx.x * blockDim.x + threadIdx.x;
    float term = 0.f;
    if (i < NEDGE) {
        int i0 = e[i];
        int i1 = e[NEDGE + i];
        const float* xv = xvec + (size_t)i0 * 16;
        const float* yv = yvec + (size_t)(i1 + y_off) * 16;
        float d2 = 0.f;
#pragma unroll
        for (int c = 0; c < 16; c += 4) {
            float4 xq = *(const float4*)(xv + c);
            float4 yq = *(const float4*)(yv + c);
            float dx = xq.x - yq.x; d2 = fmaf(dx, dx, d2);
            float dy = xq.y - yq.y; d2 = fmaf(dy, dy, d2);
            float dz = xq.z - yq.z; d2 = fmaf(dz, dz, d2);
            float dw = xq.w - yq.w; d2 = fmaf(dw, dw, d2);
        }
        term = w[i0] + w[i1 + w1_off] - sqrtf(d2 + 1e-12f);
    }
    float bs = block_reduce_sum_256(term, red);
    if (threadIdx.x == 0) atomicAdd(acc, (double)bs);
}

// ---------------- fused pairwise (non-link) kernel ----------------
// z=0: pp modality (rows p_star_nodes/gamma, cols p_nodes/gamma+N_PP, triu k=1)
// z=1: ap modality (rows p_star_nodes/beta, cols a_nodes/beta, full)
// All values stored in LDS pre-scaled by SCALE=log2(e) so the epilogue is a
// raw v_exp_f32 of (gx + gy - sqrt(sq)).
__global__ __launch_bounds__(256) void pair_kernel(
        const float* __restrict__ p, const float* __restrict__ p_star,
        const float* __restrict__ a, const float* __restrict__ beta,
        const float* __restrict__ gamma,
        const int* __restrict__ psn, const int* __restrict__ pn,
        const int* __restrict__ an, double* __restrict__ acc)
{
    const int bx = blockIdx.x, by = blockIdx.y, z = blockIdx.z;
    const bool pp = (z == 0);
    if (pp && bx < by) return;           // strictly-below-diagonal block: all masked
    const bool diag = pp && (bx == by);

    const float* X  = p_star;
    const float* Y  = pp ? p : a;
    const float* wv = pp ? gamma : beta;
    const int*   xn = psn;
    const int*   yn = pp ? pn : an;
    const int wyo   = pp ? N_PP : 0;     // weight offset for column nodes
    const int yvo   = pp ? 0 : -N_PP;    // vector offset for column nodes
    double* accp    = acc + (pp ? 1 : 3);

    __shared__ float xs[KD][TILE];
    __shared__ float ys[KD][TILE];
    __shared__ float xxs[TILE], yys[TILE], gxs[TILE], gys[TILE];
    __shared__ float red[4];

    const int t = threadIdx.x;
    // ---- load 128 x-rows (threads 0..127) and 128 y-rows (threads 128..255),
    //      transposed into LDS, pre-scaled by SCALE; also |v|^2 and weights ----
    {
        const bool isx = (t < 128);
        const int  r   = isx ? t : (t - 128);
        const int  node = isx ? xn[by * TILE + r] : yn[bx * TILE + r];
        const float* src = isx ? (X + (size_t)node * 16)
                               : (Y + (size_t)(node + yvo) * 16);
        float ss = 0.f;
        float* col = isx ? &xs[0][r] : &ys[0][r];
#pragma unroll
        for (int c = 0; c < 16; c += 4) {
            float4 v = *(const float4*)(src + c);
            float v0 = v.x * SCALE, v1 = v.y * SCALE, v2 = v.z * SCALE, v3 = v.w * SCALE;
            col[(c + 0) * TILE] = v0;
            col[(c + 1) * TILE] = v1;
            col[(c + 2) * TILE] = v2;
            col[(c + 3) * TILE] = v3;
            ss = fmaf(v0, v0, ss); ss = fmaf(v1, v1, ss);
            ss = fmaf(v2, v2, ss); ss = fmaf(v3, v3, ss);
        }
        if (isx) {
            xxs[r] = ss;
            gxs[r] = wv[node] * SCALE;
        } else {
            yys[r] = ss;
            gys[r] = wv[node + wyo] * SCALE;
        }
    }
    __syncthreads();

    // ---- 8x8 register tile per thread ----
    const int tx = t & 15;    // col group: cols tx*8 .. tx*8+7
    const int ty = t >> 4;    // row group: rows ty*8 .. ty*8+7

    float acc8[8][8];
#pragma unroll
    for (int i = 0; i < 8; ++i)
#pragma unroll
        for (int j = 0; j < 8; ++j) acc8[i][j] = 0.f;

#pragma unroll
    for (int k = 0; k < KD; ++k) {
        float4 xa = *(const float4*)&xs[k][ty * 8];
        float4 xb = *(const float4*)&xs[k][ty * 8 + 4];
        float4 ya = *(const float4*)&ys[k][tx * 8];
        float4 yb = *(const float4*)&ys[k][tx * 8 + 4];
        float xr[8] = {xa.x, xa.y, xa.z, xa.w, xb.x, xb.y, xb.z, xb.w};
        float yr[8] = {ya.x, ya.y, ya.z, ya.w, yb.x, yb.y, yb.z, yb.w};
#pragma unroll
        for (int i = 0; i < 8; ++i)
#pragma unroll
            for (int j = 0; j < 8; ++j)
                acc8[i][j] = fmaf(xr[i], yr[j], acc8[i][j]);
    }

    // row/col statistics into registers
    float xxr[8], yyr[8], gxr[8], gyr[8];
#pragma unroll
    for (int d = 0; d < 8; ++d) {
        xxr[d] = xxs[ty * 8 + d];
        yyr[d] = yys[tx * 8 + d];
        gxr[d] = gxs[ty * 8 + d];
        gyr[d] = gys[tx * 8 + d];
    }

    float sum = 0.f;
    if (!diag) {
#pragma unroll
        for (int i = 0; i < 8; ++i) {
#pragma unroll
            for (int j = 0; j < 8; ++j) {
                float sq   = fmaf(-2.f, acc8[i][j], xxr[i] + yyr[j]);
                float dist = FAST_SQRT(fmaxf(sq, EPS2));
                sum += FAST_EXP2(gxr[i] + gyr[j] - dist);
            }
        }
    } else {
#pragma unroll
        for (int i = 0; i < 8; ++i) {
#pragma unroll
            for (int j = 0; j < 8; ++j) {
                float sq   = fmaf(-2.f, acc8[i][j], xxr[i] + yyr[j]);
                float dist = FAST_SQRT(fmaxf(sq, EPS2));
                float v    = FAST_EXP2(gxr[i] + gyr[j] - dist);
                sum += ((tx * 8 + j) > (ty * 8 + i)) ? v : 0.f;
            }
        }
    }

    float bs = block_reduce_sum_256(sum, red);
    if (t == 0) atomicAdd(accp, (double)bs);
}

// ---------------- finalize ----------------
__global__ void finalize_kernel(const double* __restrict__ acc, float* __restrict__ out)
{
    double nll_pp = -(acc[0] - acc[1]);
    double nll_ap = -(acc[2] - acc[3]);
    out[0] = (float)(0.5 * nll_pp / (double)BSZ + 0.5 * nll_ap / (double)BSZ);
}

extern "C" void kernel_launch(void* const* d_in, const int* in_sizes, int n_in,
                              void* d_out, int out_size, void* d_ws, size_t ws_size,
                              hipStream_t stream)
{
    const float* p       = (const float*)d_in[0];
    const float* p_star  = (const float*)d_in[1];
    const float* a       = (const float*)d_in[2];
    const float* beta    = (const float*)d_in[3];
    const float* gamma   = (const float*)d_in[4];
    const int* edges_pp  = (const int*)d_in[5];
    const int* edges_ap  = (const int*)d_in[6];
    const int* psn       = (const int*)d_in[7];
    const int* pn        = (const int*)d_in[8];
    const int* an        = (const int*)d_in[9];

    double* acc = (double*)d_ws;
    hipMemsetAsync(d_ws, 0, 4 * sizeof(double), stream);

    dim3 grid(BSZ / TILE, BSZ / TILE, 2);
    pair_kernel<<<grid, 256, 0, stream>>>(p, p_star, a, beta, gamma,
                                          psn, pn, an, acc);

    int eb = (NEDGE + 255) / 256;
    edge_kernel<<<eb, 256, 0, stream>>>(p_star, p, gamma, edges_pp, N_PP, 0, acc + 0);
    edge_kernel<<<eb, 256, 0, stream>>>(p_star, a, beta, edges_ap, 0, -N_PP, acc + 2);

    finalize_kernel<<<1, 1, 0, stream>>>(acc, (float*)d_out);
}

// Round 3
// 145.945 us; speedup vs baseline: 2.6555x; 1.1241x over previous
//
#include <hip/hip_runtime.h>

#define N_PP 100000
#define NEDGE 500000
#define BSZ 8192
#define TILE 128
#define SCALE 1.44269504088896f   // log2(e)

typedef __attribute__((ext_vector_type(8)))  short bf16x8;
typedef __attribute__((ext_vector_type(16))) float f32x16;
typedef __attribute__((ext_vector_type(4)))  float f32x4;

#if __has_builtin(__builtin_amdgcn_sqrtf)
#define FAST_SQRT(x) __builtin_amdgcn_sqrtf(x)
#else
#define FAST_SQRT(x) sqrtf(x)
#endif
#if __has_builtin(__builtin_amdgcn_exp2f)
#define FAST_EXP2(x) __builtin_amdgcn_exp2f(x)
#else
#define FAST_EXP2(x) exp2f(x)
#endif

__device__ __forceinline__ unsigned short f2bf(float f) {
    unsigned u = __builtin_bit_cast(unsigned, f);
    u += 0x7FFFu + ((u >> 16) & 1u);     // round-to-nearest-even
    return (unsigned short)(u >> 16);
}
__device__ __forceinline__ float bf2f(unsigned short s) {
    unsigned u = ((unsigned)s) << 16;
    return __builtin_bit_cast(float, u);
}

__device__ __forceinline__ bf16x8 load_frag(const float* __restrict__ src) {
    float4 v0 = *(const float4*)src;
    float4 v1 = *(const float4*)(src + 4);
    bf16x8 f;
    f[0] = (short)f2bf(v0.x); f[1] = (short)f2bf(v0.y);
    f[2] = (short)f2bf(v0.z); f[3] = (short)f2bf(v0.w);
    f[4] = (short)f2bf(v1.x); f[5] = (short)f2bf(v1.y);
    f[6] = (short)f2bf(v1.z); f[7] = (short)f2bf(v1.w);
    return f;
}

__device__ __forceinline__ float pdist16(const float* __restrict__ xv,
                                         const float* __restrict__ yv) {
    float d2 = 1e-12f;
#pragma unroll
    for (int c = 0; c < 16; c += 4) {
        float4 xq = *(const float4*)(xv + c);
        float4 yq = *(const float4*)(yv + c);
        float dx = xq.x - yq.x; d2 = fmaf(dx, dx, d2);
        float dy = xq.y - yq.y; d2 = fmaf(dy, dy, d2);
        float dz = xq.z - yq.z; d2 = fmaf(dz, dz, d2);
        float dw = xq.w - yq.w; d2 = fmaf(dw, dw, d2);
    }
    return sqrtf(d2);
}

__device__ __forceinline__ float block_reduce_sum_256(float v, float* red) {
#pragma unroll
    for (int o = 32; o > 0; o >>= 1) v += __shfl_down(v, o, 64);
    __syncthreads();                     // protect red[] reuse
    if ((threadIdx.x & 63) == 0) red[threadIdx.x >> 6] = v;
    __syncthreads();
    return red[0] + red[1] + red[2] + red[3];
}

// epilogue over one row-tile (32 rows) x two col-tiles, 16 regs per acc
template <bool DIAG>
__device__ __forceinline__ float epi_rt(
        const f32x16& ca, const f32x16& cb,
        const float* __restrict__ xxs, const float* __restrict__ gxs,
        int rb, float yy0, float gy0, float yy1, float gy1,
        int cj0, int cj1)
{
    f32x4 xxq[4], gxq[4];
#pragma unroll
    for (int q = 0; q < 4; ++q) {
        xxq[q] = *(const f32x4*)&xxs[rb + q * 8];
        gxq[q] = *(const f32x4*)&gxs[rb + q * 8];
    }
    float s = 0.f;
#pragma unroll
    for (int q = 0; q < 4; ++q) {
#pragma unroll
        for (int j = 0; j < 4; ++j) {
            const int reg = q * 4 + j;
            float sxy = xxq[q][j];
            float gx  = gxq[q][j];
            float sq0 = fmaf(-2.f, ca[reg], sxy + yy0);
            float d0  = FAST_SQRT(fmaxf(sq0, 1e-12f));
            float v0  = FAST_EXP2(fmaf(-SCALE, d0, gx + gy0));
            float sq1 = fmaf(-2.f, cb[reg], sxy + yy1);
            float d1  = FAST_SQRT(fmaxf(sq1, 1e-12f));
            float v1  = FAST_EXP2(fmaf(-SCALE, d1, gx + gy1));
            if (DIAG) {
                int row = rb + q * 8 + j;
                v0 = (cj0 > row) ? v0 : 0.f;
                v1 = (cj1 > row) ? v1 : 0.f;
            }
            s += v0 + v1;
        }
    }
    return s;
}

__global__ __launch_bounds__(256) void fused_kernel(
        const float* __restrict__ p, const float* __restrict__ p_star,
        const float* __restrict__ a, const float* __restrict__ beta,
        const float* __restrict__ gamma,
        const int* __restrict__ edges_pp, const int* __restrict__ edges_ap,
        const int* __restrict__ psn, const int* __restrict__ pn,
        const int* __restrict__ an, double* __restrict__ acc)
{
    __shared__ float xxs[TILE], gxs[TILE], yys[TILE], gys[TILE];
    __shared__ float red[4];

    const int bx = blockIdx.x, by = blockIdx.y, z = blockIdx.z;
    const int t = threadIdx.x;

    if (z == 0 && bx < by) {
        // ---------- repurposed idle blocks: edge (link) terms ----------
        int u = (by * (by - 1)) / 2 + bx;      // 0 .. 2015
        int i = u * 256 + t;                   // 0 .. 516095
        float tpp = 0.f, tap = 0.f;
        if (i < NEDGE) {
            int e0 = edges_pp[i], e1 = edges_pp[NEDGE + i];
            tpp = gamma[e0] + gamma[e1 + N_PP]
                - pdist16(p_star + (size_t)e0 * 16, p + (size_t)e1 * 16);
            int f0 = edges_ap[i], f1 = edges_ap[NEDGE + i];
            tap = beta[f0] + beta[f1]
                - pdist16(p_star + (size_t)f0 * 16, a + (size_t)(f1 - N_PP) * 16);
        }
        float s0 = block_reduce_sum_256(tpp, red);
        if (t == 0) atomicAdd(acc + 0, (double)s0);
        float s1 = block_reduce_sum_256(tap, red);
        if (t == 0) atomicAdd(acc + 2, (double)s1);
        return;
    }

    // ---------- pairwise (non-link) blocks ----------
    const bool pp   = (z == 0);
    const bool diag = pp && (bx == by);
    const float* Y  = pp ? p : a;
    const float* wv = pp ? gamma : beta;
    const int* yn   = pp ? pn : an;
    const int wyo   = pp ? N_PP : 0;    // weight offset for col nodes
    const int yvo   = pp ? 0 : -N_PP;   // vector offset for col nodes
    double* accp    = acc + (pp ? 1 : 3);

    const int l  = t & 63, w = t >> 6;
    const int wr = w >> 1, wc = w & 1;  // wave -> 64x64 sub-tile
    const int l31 = l & 31, h = l >> 5; // MFMA lane decomposition

    // fragment gathers straight from global (L2-resident tables)
    const int ar0 = by * TILE + wr * 64 + l31;
    const int ar1 = ar0 + 32;
    const int an0 = psn[ar0], an1 = psn[ar1];
    bf16x8 aF0 = load_frag(p_star + (size_t)an0 * 16 + h * 8);
    bf16x8 aF1 = load_frag(p_star + (size_t)an1 * 16 + h * 8);
    const int bc0 = bx * TILE + wc * 64 + l31;
    const int bc1 = bc0 + 32;
    const int bn0 = yn[bc0], bn1 = yn[bc1];
    bf16x8 bF0 = load_frag(Y + (size_t)(bn0 + yvo) * 16 + h * 8);
    bf16x8 bF1 = load_frag(Y + (size_t)(bn1 + yvo) * 16 + h * 8);

    // per-row stats: ||x~||^2 from the SAME bf16 rounding, weight * log2(e)
    {
        const bool isx = (t < 128);
        const int  r   = isx ? t : t - 128;
        const int  node = isx ? psn[by * TILE + r] : yn[bx * TILE + r];
        const float* src = isx ? (p_star + (size_t)node * 16)
                               : (Y + (size_t)(node + yvo) * 16);
        float ss = 0.f;
#pragma unroll
        for (int c = 0; c < 16; c += 4) {
            float4 v = *(const float4*)(src + c);
            float q0 = bf2f(f2bf(v.x)), q1 = bf2f(f2bf(v.y));
            float q2 = bf2f(f2bf(v.z)), q3 = bf2f(f2bf(v.w));
            ss = fmaf(q0, q0, ss); ss = fmaf(q1, q1, ss);
            ss = fmaf(q2, q2, ss); ss = fmaf(q3, q3, ss);
        }
        if (isx) { xxs[r] = ss; gxs[r] = wv[node] * SCALE; }
        else     { yys[r] = ss; gys[r] = wv[node + wyo] * SCALE; }
    }
    __syncthreads();

    // 4 MFMAs: 64x64 output per wave, K=16 in one shot
    f32x16 c00, c01, c10, c11;
#pragma unroll
    for (int i = 0; i < 16; ++i) { c00[i] = 0.f; c01[i] = 0.f; c10[i] = 0.f; c11[i] = 0.f; }
    c00 = __builtin_amdgcn_mfma_f32_32x32x16_bf16(aF0, bF0, c00, 0, 0, 0);
    c01 = __builtin_amdgcn_mfma_f32_32x32x16_bf16(aF0, bF1, c01, 0, 0, 0);
    c10 = __builtin_amdgcn_mfma_f32_32x32x16_bf16(aF1, bF0, c10, 0, 0, 0);
    c11 = __builtin_amdgcn_mfma_f32_32x32x16_bf16(aF1, bF1, c11, 0, 0, 0);

    const int cj0 = wc * 64 + l31, cj1 = cj0 + 32;
    const float yy0 = yys[cj0], gy0 = gys[cj0];
    const float yy1 = yys[cj1], gy1 = gys[cj1];
    const int rb0 = wr * 64 + 4 * h;   // rows rb0 + 8q + j  (q,j in 0..3)
    const int rb1 = rb0 + 32;

    float sum;
    if (diag) {
        sum = epi_rt<true >(c00, c01, xxs, gxs, rb0, yy0, gy0, yy1, gy1, cj0, cj1)
            + epi_rt<true >(c10, c11, xxs, gxs, rb1, yy0, gy0, yy1, gy1, cj0, cj1);
    } else {
        sum = epi_rt<false>(c00, c01, xxs, gxs, rb0, yy0, gy0, yy1, gy1, cj0, cj1)
            + epi_rt<false>(c10, c11, xxs, gxs, rb1, yy0, gy0, yy1, gy1, cj0, cj1);
    }

    float bs = block_reduce_sum_256(sum, red);
    if (t == 0) atomicAdd(accp, (double)bs);
}

__global__ void finalize_kernel(const double* __restrict__ acc, float* __restrict__ out)
{
    double nll_pp = -(acc[0] - acc[1]);
    double nll_ap = -(acc[2] - acc[3]);
    out[0] = (float)(0.5 * nll_pp / (double)BSZ + 0.5 * nll_ap / (double)BSZ);
}

extern "C" void kernel_launch(void* const* d_in, const int* in_sizes, int n_in,
                              void* d_out, int out_size, void* d_ws, size_t ws_size,
                              hipStream_t stream)
{
    const float* p       = (const float*)d_in[0];
    const float* p_star  = (const float*)d_in[1];
    const float* a       = (const float*)d_in[2];
    const float* beta    = (const float*)d_in[3];
    const float* gamma   = (const float*)d_in[4];
    const int* edges_pp  = (const int*)d_in[5];
    const int* edges_ap  = (const int*)d_in[6];
    const int* psn       = (const int*)d_in[7];
    const int* pn        = (const int*)d_in[8];
    const int* an        = (const int*)d_in[9];

    double* acc = (double*)d_ws;
    hipMemsetAsync(d_ws, 0, 4 * sizeof(double), stream);

    dim3 grid(BSZ / TILE, BSZ / TILE, 2);
    fused_kernel<<<grid, 256, 0, stream>>>(p, p_star, a, beta, gamma,
                                           edges_pp, edges_ap, psn, pn, an, acc);

    finalize_kernel<<<1, 1, 0, stream>>>(acc, (float*)d_out);
}